// Round 6
// baseline (1364.058 us; speedup 1.0000x reference)
//
#include <hip/hip_runtime.h>
#include <hip/hip_cooperative_groups.h>
#include <math.h>

namespace cg = cooperative_groups;

// Problem constants (fixed by reference).
#define TOKENS      16384     // 8 * 2048
#define HID         2048
#define EXPERTS     64
#define CAPSLOT     1024      // per-expert list cap; counts ~Binom(16384,1/64)=256±16
#define CAP         512       // expert_capacity = 2*ceil(16384/64)

__device__ __forceinline__ void fma8(float* a, float s, float4 w0, float4 w1) {
    a[0] = fmaf(s, w0.x, a[0]); a[1] = fmaf(s, w0.y, a[1]);
    a[2] = fmaf(s, w0.z, a[2]); a[3] = fmaf(s, w0.w, a[3]);
    a[4] = fmaf(s, w1.x, a[4]); a[5] = fmaf(s, w1.y, a[5]);
    a[6] = fmaf(s, w1.z, a[6]); a[7] = fmaf(s, w1.w, a[7]);
}

// ===========================================================================
// FUSED cooperative kernel: all 4 phases, grid.sync() between them.
// Grid = 64 * KSPLIT blocks x 256 thr. KCH=128: 1024 blocks, 32 KB LDS,
// __launch_bounds__(256,4) caps VGPR at 128 (phase-1 demand measured 100 in
// r5 -> no spill) -> 4 blocks/CU, 16 waves/CU, 4 waves/SIMD: r5's k_partial
// was latency-bound at 2 waves/SIMD (VALUBusy 37%), TLP doubles again.
// Phases:
//  P1 partial GEMM (r5-proven body: W chunk in LDS, barrier-free k-loop,
//     8tok x 8exp tile, prefetch-1 x)          -> partial[kc][token][e]
//  P2 reduce KSPLIT chunks + softmax + top1/2 + bucket append (r5 k_route)
//  P3 per-expert O(n^2) rank on pre-built buckets (r5 k_rank)
//  P4 materialize [mask | gates]               (r5 k_out)
// Residual analysis r4/r5: ~145us of total is roughly dispatch-count-
// proportional overhead -> 4 dispatches -> 1.
// ===========================================================================
template<int KCH>
__global__ __launch_bounds__(256, 4) void k_fused(
    const float* __restrict__ x, const float* __restrict__ W,
    float* __restrict__ partial,
    float* __restrict__ p1o, float* __restrict__ p2o,
    int* __restrict__ top1o, int* __restrict__ top2o,
    int* __restrict__ cnts, float* __restrict__ bkey, int* __restrict__ btok,
    int* __restrict__ keep1, int* __restrict__ keep2,
    float* __restrict__ out)
{
    constexpr int KSPLIT = HID / KCH;
    __shared__ float smem[KCH * EXPERTS];   // P1: W chunk; P3: skey/stok (8KB)

    cg::grid_group grid = cg::this_grid();
    const int tid = threadIdx.x;

    // ---------------- P1: partial GEMM ----------------
    {
        const int tb = blockIdx.x & 63;       // token block (256 tokens)
        const int kc = blockIdx.x >> 6;       // k chunk 0..KSPLIT-1
        const int k0 = kc * KCH;

        if (blockIdx.x == 0) {                // zero bucket counters for P2
            for (int i = tid; i < 128 * 16; i += 256) cnts[i] = 0;
        }

        // stage W chunk, coalesced float4
        {
            const float4* src = (const float4*)(W + (size_t)k0 * EXPERTS);
            float4* dst = (float4*)smem;
            #pragma unroll
            for (int i = 0; i < (KCH * EXPERTS / 4) / 256; ++i)
                dst[i * 256 + tid] = src[i * 256 + tid];
        }
        __syncthreads();

        const int lane = tid & 63;
        const int wv   = tid >> 6;            // wave 0..3
        const int tg   = lane >> 3;           // token group 0..7
        const int eg   = lane & 7;            // expert group 0..7
        const int tok0 = tb * 256 + wv * 64 + tg * 8;
        const float* xb = x + (size_t)tok0 * HID + k0;

        float acc[8][8];
        #pragma unroll
        for (int i = 0; i < 8; ++i)
            #pragma unroll
            for (int e = 0; e < 8; ++e) acc[i][e] = 0.f;

        float4 xv[8];
        #pragma unroll
        for (int i = 0; i < 8; ++i)
            xv[i] = *(const float4*)(xb + (size_t)i * HID);

        #pragma unroll 2
        for (int k4 = 0; k4 < KCH; k4 += 4) {
            float4 xn[8];
            const bool more = (k4 + 4 < KCH);
            if (more) {
                #pragma unroll
                for (int i = 0; i < 8; ++i)
                    xn[i] = *(const float4*)(xb + (size_t)i * HID + k4 + 4);
            }

            float4 w0[4], w1[4];
            #pragma unroll
            for (int kk = 0; kk < 4; ++kk) {
                const float* wp = &smem[(k4 + kk) * EXPERTS + eg * 8];
                w0[kk] = *(const float4*)wp;
                w1[kk] = *(const float4*)(wp + 4);
            }

            #pragma unroll
            for (int i = 0; i < 8; ++i) {
                fma8(acc[i], xv[i].x, w0[0], w1[0]);
                fma8(acc[i], xv[i].y, w0[1], w1[1]);
                fma8(acc[i], xv[i].z, w0[2], w1[2]);
                fma8(acc[i], xv[i].w, w0[3], w1[3]);
            }

            if (more) {
                #pragma unroll
                for (int i = 0; i < 8; ++i) xv[i] = xn[i];
            }
        }

        float* pb = partial + ((size_t)kc * TOKENS + tok0) * EXPERTS + eg * 8;
        #pragma unroll
        for (int i = 0; i < 8; ++i) {
            *(float4*)(pb + (size_t)i * EXPERTS) =
                make_float4(acc[i][0], acc[i][1], acc[i][2], acc[i][3]);
            *(float4*)(pb + (size_t)i * EXPERTS + 4) =
                make_float4(acc[i][4], acc[i][5], acc[i][6], acc[i][7]);
        }
    }

    grid.sync();

    // ---------------- P2: reduce + softmax + top1/top2 + bucket append ----
    for (int grp = blockIdx.x; grp < TOKENS / 4; grp += gridDim.x) {
        const int e     = tid & 63;
        const int token = grp * 4 + (tid >> 6);

        float logit = 0.f;
        #pragma unroll
        for (int c = 0; c < KSPLIT; ++c)
            logit += partial[((size_t)c * TOKENS + token) * EXPERTS + e];

        // top-1 argmax, first-index tie-break
        float bv = logit; int be = e;
        #pragma unroll
        for (int m = 32; m >= 1; m >>= 1) {
            float ov = __shfl_xor(bv, m);
            int   oe = __shfl_xor(be, m);
            if (ov > bv || (ov == bv && oe < be)) { bv = ov; be = oe; }
        }
        const float m1 = bv;
        const int   e1 = be;

        // top-2: argmax excluding e1
        float bv2 = (e == e1) ? -INFINITY : logit;
        int   be2 = (e == e1) ? (1 << 30) : e;
        #pragma unroll
        for (int m = 32; m >= 1; m >>= 1) {
            float ov = __shfl_xor(bv2, m);
            int   oe = __shfl_xor(be2, m);
            if (ov > bv2 || (ov == bv2 && oe < be2)) { bv2 = ov; be2 = oe; }
        }
        const int e2 = be2;

        // softmax denominator (max-subtracted)
        float s = expf(logit - m1);
        #pragma unroll
        for (int m = 32; m >= 1; m >>= 1) s += __shfl_xor(s, m);

        if (e == 0) {
            const float P1 = 1.0f / s;          // max softmax prob (sort key)
            p1o[token]   = P1;
            p2o[token]   = expf(bv2 - m1) / s;
            top1o[token] = e1;
            top2o[token] = e2;

            // bucket appends (fill order nondeterministic; rank comparator
            // (key desc, token asc) is a strict total order -> deterministic)
            int s1 = atomicAdd(&cnts[e1 * 16], 1);
            if (s1 < CAPSLOT) {
                bkey[(size_t)e1 * CAPSLOT + s1] = P1;
                btok[(size_t)e1 * CAPSLOT + s1] = token;
            }
            int s2 = atomicAdd(&cnts[(64 + e2) * 16], 1);
            if (s2 < CAPSLOT) {
                bkey[(size_t)(64 + e2) * CAPSLOT + s2] = P1;
                btok[(size_t)(64 + e2) * CAPSLOT + s2] = token;
            }
        }
    }

    grid.sync();

    // ---------------- P3: per-expert rank -> keep flags ----
    {
        float* skey = smem;                       // reuse LDS
        int*   stok = (int*)(smem + CAPSLOT);

        for (int b = blockIdx.x; b < 128; b += gridDim.x) {
            const int mode = b >> 6;
            const int e    = b & 63;

            const int n_raw = cnts[b * 16];
            const int n     = min(n_raw, CAPSLOT);
            const int base  = mode ? cnts[e * 16] : 0;  // raw top-1 count

            __syncthreads();
            for (int i = tid; i < n; i += 256) {
                skey[i] = bkey[(size_t)b * CAPSLOT + i];
                stok[i] = btok[(size_t)b * CAPSLOT + i];
            }
            __syncthreads();

            int* __restrict__ keep = mode ? keep2 : keep1;
            for (int i = tid; i < n; i += 256) {
                const float ki = skey[i];
                const int   ti = stok[i];
                int r = base;
                for (int j = 0; j < n; ++j)
                    r += (skey[j] > ki || (skey[j] == ki && stok[j] < ti)) ? 1 : 0;
                keep[ti] = (r < CAP) ? 1 : 0;
            }
        }
    }

    grid.sync();

    // ---------------- P4: materialize [mask | gates] ----
    for (int tb = blockIdx.x; tb < TOKENS / 16; tb += gridDim.x) {
        const int token = tb * 16 + (tid >> 4);
        const int eb    = (tid & 15) * 4;

        const int  k1 = keep1[token];
        const int  k2 = keep2[token];
        const float P1 = k1 ? p1o[token] : 0.0f;
        const float P2 = k2 ? p2o[token] : 0.0f;
        const float denom = fmaxf(P1 + P2, 1.1920929e-07f);   // fp32 eps clip
        const float g1 = P1 / denom;
        const float g2 = P2 / denom;
        const int e1 = top1o[token];
        const int e2 = top2o[token];

        float4 mv, pv;
        mv.x = (k1 && e1 == eb + 0) ? 1.0f : 0.0f;
        mv.y = (k1 && e1 == eb + 1) ? 1.0f : 0.0f;
        mv.z = (k1 && e1 == eb + 2) ? 1.0f : 0.0f;
        mv.w = (k1 && e1 == eb + 3) ? 1.0f : 0.0f;
        pv.x = (k1 && e1 == eb + 0) ? g1 : ((k2 && e2 == eb + 0) ? g2 : 0.0f);
        pv.y = (k1 && e1 == eb + 1) ? g1 : ((k2 && e2 == eb + 1) ? g2 : 0.0f);
        pv.z = (k1 && e1 == eb + 2) ? g1 : ((k2 && e2 == eb + 2) ? g2 : 0.0f);
        pv.w = (k1 && e1 == eb + 3) ? g1 : ((k2 && e2 == eb + 3) ? g2 : 0.0f);

        *(float4*)(out + (size_t)token * EXPERTS + eb) = mv;
        *(float4*)(out + (size_t)TOKENS * EXPERTS + (size_t)token * EXPERTS + eb) = pv;
    }
}

// ===========================================================================
// Classic 4-kernel fallback (r5-proven) — used if cooperative launch fails.
// ===========================================================================
template<int KCH>
__global__ __launch_bounds__(256) void k_partial(
    const float* __restrict__ x, const float* __restrict__ W,
    float* __restrict__ partial, int* __restrict__ cnts)
{
    __shared__ float wl[KCH * EXPERTS];

    const int tid = threadIdx.x;
    const int tb = blockIdx.x & 63;
    const int kc = blockIdx.x >> 6;
    const int k0 = kc * KCH;

    if (blockIdx.x == 0) {
        for (int i = tid; i < 128 * 16; i += 256) cnts[i] = 0;
    }

    {
        const float4* src = (const float4*)(W + (size_t)k0 * EXPERTS);
        float4* dst = (float4*)wl;
        #pragma unroll
        for (int i = 0; i < (KCH * EXPERTS / 4) / 256; ++i)
            dst[i * 256 + tid] = src[i * 256 + tid];
    }
    __syncthreads();

    const int lane = tid & 63;
    const int wv   = tid >> 6;
    const int tg   = lane >> 3;
    const int eg   = lane & 7;
    const int tok0 = tb * 256 + wv * 64 + tg * 8;
    const float* xb = x + (size_t)tok0 * HID + k0;

    float acc[8][8];
    #pragma unroll
    for (int i = 0; i < 8; ++i)
        #pragma unroll
        for (int e = 0; e < 8; ++e) acc[i][e] = 0.f;

    float4 xv[8];
    #pragma unroll
    for (int i = 0; i < 8; ++i)
        xv[i] = *(const float4*)(xb + (size_t)i * HID);

    #pragma unroll 2
    for (int k4 = 0; k4 < KCH; k4 += 4) {
        float4 xn[8];
        const bool more = (k4 + 4 < KCH);
        if (more) {
            #pragma unroll
            for (int i = 0; i < 8; ++i)
                xn[i] = *(const float4*)(xb + (size_t)i * HID + k4 + 4);
        }

        float4 w0[4], w1[4];
        #pragma unroll
        for (int kk = 0; kk < 4; ++kk) {
            const float* wp = &wl[(k4 + kk) * EXPERTS + eg * 8];
            w0[kk] = *(const float4*)wp;
            w1[kk] = *(const float4*)(wp + 4);
        }

        #pragma unroll
        for (int i = 0; i < 8; ++i) {
            fma8(acc[i], xv[i].x, w0[0], w1[0]);
            fma8(acc[i], xv[i].y, w0[1], w1[1]);
            fma8(acc[i], xv[i].z, w0[2], w1[2]);
            fma8(acc[i], xv[i].w, w0[3], w1[3]);
        }

        if (more) {
            #pragma unroll
            for (int i = 0; i < 8; ++i) xv[i] = xn[i];
        }
    }

    float* pb = partial + ((size_t)kc * TOKENS + tok0) * EXPERTS + eg * 8;
    #pragma unroll
    for (int i = 0; i < 8; ++i) {
        *(float4*)(pb + (size_t)i * EXPERTS) =
            make_float4(acc[i][0], acc[i][1], acc[i][2], acc[i][3]);
        *(float4*)(pb + (size_t)i * EXPERTS + 4) =
            make_float4(acc[i][4], acc[i][5], acc[i][6], acc[i][7]);
    }
}

template<int KSPLIT>
__global__ __launch_bounds__(256) void k_route(
    const float* __restrict__ partial,
    float* __restrict__ p1o, float* __restrict__ p2o,
    int* __restrict__ top1o, int* __restrict__ top2o,
    int* __restrict__ cnts, float* __restrict__ bkey, int* __restrict__ btok)
{
    const int tid   = threadIdx.x;
    const int e     = tid & 63;
    const int token = blockIdx.x * 4 + (tid >> 6);

    float logit = 0.f;
    #pragma unroll
    for (int c = 0; c < KSPLIT; ++c)
        logit += partial[((size_t)c * TOKENS + token) * EXPERTS + e];

    float bv = logit; int be = e;
    #pragma unroll
    for (int m = 32; m >= 1; m >>= 1) {
        float ov = __shfl_xor(bv, m);
        int   oe = __shfl_xor(be, m);
        if (ov > bv || (ov == bv && oe < be)) { bv = ov; be = oe; }
    }
    const float m1 = bv;
    const int   e1 = be;

    float bv2 = (e == e1) ? -INFINITY : logit;
    int   be2 = (e == e1) ? (1 << 30) : e;
    #pragma unroll
    for (int m = 32; m >= 1; m >>= 1) {
        float ov = __shfl_xor(bv2, m);
        int   oe = __shfl_xor(be2, m);
        if (ov > bv2 || (ov == bv2 && oe < be2)) { bv2 = ov; be2 = oe; }
    }
    const int e2 = be2;

    float s = expf(logit - m1);
    #pragma unroll
    for (int m = 32; m >= 1; m >>= 1) s += __shfl_xor(s, m);

    if (e == 0) {
        const float P1 = 1.0f / s;
        p1o[token]   = P1;
        p2o[token]   = expf(bv2 - m1) / s;
        top1o[token] = e1;
        top2o[token] = e2;

        int s1 = atomicAdd(&cnts[e1 * 16], 1);
        if (s1 < CAPSLOT) {
            bkey[(size_t)e1 * CAPSLOT + s1] = P1;
            btok[(size_t)e1 * CAPSLOT + s1] = token;
        }
        int s2 = atomicAdd(&cnts[(64 + e2) * 16], 1);
        if (s2 < CAPSLOT) {
            bkey[(size_t)(64 + e2) * CAPSLOT + s2] = P1;
            btok[(size_t)(64 + e2) * CAPSLOT + s2] = token;
        }
    }
}

__global__ __launch_bounds__(256) void k_rank(
    const int* __restrict__ cnts,
    const float* __restrict__ bkey, const int* __restrict__ btok,
    int* __restrict__ keep1, int* __restrict__ keep2)
{
    __shared__ float skey[CAPSLOT];
    __shared__ int   stok[CAPSLOT];

    const int b    = blockIdx.x;
    const int mode = b >> 6;
    const int e    = b & 63;
    const int tid  = threadIdx.x;

    const int n_raw = cnts[b * 16];
    const int n     = min(n_raw, CAPSLOT);
    const int base  = mode ? cnts[e * 16] : 0;

    for (int i = tid; i < n; i += 256) {
        skey[i] = bkey[(size_t)b * CAPSLOT + i];
        stok[i] = btok[(size_t)b * CAPSLOT + i];
    }
    __syncthreads();

    int* __restrict__ keep = mode ? keep2 : keep1;
    for (int i = tid; i < n; i += 256) {
        const float ki = skey[i];
        const int   ti = stok[i];
        int r = base;
        for (int j = 0; j < n; ++j)
            r += (skey[j] > ki || (skey[j] == ki && stok[j] < ti)) ? 1 : 0;
        keep[ti] = (r < CAP) ? 1 : 0;
    }
}

__global__ __launch_bounds__(256) void k_out(
    const float* __restrict__ p1, const float* __restrict__ p2,
    const int* __restrict__ top1, const int* __restrict__ top2,
    const int* __restrict__ keep1, const int* __restrict__ keep2,
    float* __restrict__ out)
{
    const int tid   = threadIdx.x;
    const int token = blockIdx.x * 16 + (tid >> 4);
    const int eb    = (tid & 15) * 4;

    const int  k1 = keep1[token];
    const int  k2 = keep2[token];
    const float P1 = k1 ? p1[token] : 0.0f;
    const float P2 = k2 ? p2[token] : 0.0f;
    const float denom = fmaxf(P1 + P2, 1.1920929e-07f);
    const float g1 = P1 / denom;
    const float g2 = P2 / denom;
    const int e1 = top1[token];
    const int e2 = top2[token];

    float4 mv, pv;
    mv.x = (k1 && e1 == eb + 0) ? 1.0f : 0.0f;
    mv.y = (k1 && e1 == eb + 1) ? 1.0f : 0.0f;
    mv.z = (k1 && e1 == eb + 2) ? 1.0f : 0.0f;
    mv.w = (k1 && e1 == eb + 3) ? 1.0f : 0.0f;
    pv.x = (k1 && e1 == eb + 0) ? g1 : ((k2 && e2 == eb + 0) ? g2 : 0.0f);
    pv.y = (k1 && e1 == eb + 1) ? g1 : ((k2 && e2 == eb + 1) ? g2 : 0.0f);
    pv.z = (k1 && e1 == eb + 2) ? g1 : ((k2 && e2 == eb + 2) ? g2 : 0.0f);
    pv.w = (k1 && e1 == eb + 3) ? g1 : ((k2 && e2 == eb + 3) ? g2 : 0.0f);

    *(float4*)(out + (size_t)token * EXPERTS + eb) = mv;
    *(float4*)(out + (size_t)TOKENS * EXPERTS + (size_t)token * EXPERTS + eb) = pv;
}

// ---------------------------------------------------------------------------
extern "C" void kernel_launch(void* const* d_in, const int* in_sizes, int n_in,
                              void* d_out, int out_size, void* d_ws, size_t ws_size,
                              hipStream_t stream)
{
    const float* x = (const float*)d_in[0];   // (8,2048,2048) fp32
    const float* W = (const float*)d_in[1];   // (2048,64) fp32
    float* out = (float*)d_out;               // 2 * 16384 * 64 fp32

    // extras: p1,p2 + top1,top2,keep1,keep2 + cnts + buckets  (~1.45 MB)
    const size_t extras_f = 6 * (size_t)TOKENS + 128 * 16
                          + 2 * 128 * (size_t)CAPSLOT;
    const size_t need16 = ((size_t)16 * TOKENS * EXPERTS + extras_f) * 4;
    const size_t need8  = ((size_t)8  * TOKENS * EXPERTS + extras_f) * 4;

    int ks;
    if (ws_size == 0 || ws_size >= need16) ks = 16;
    else if (ws_size >= need8)             ks = 8;
    else                                   ks = 4;

    float* partial = (float*)d_ws;            // ks * TOKENS * EXPERTS floats
    float* p1    = partial + (size_t)ks * TOKENS * EXPERTS;
    float* p2    = p1 + TOKENS;
    int*   top1  = (int*)(p2 + TOKENS);
    int*   top2  = top1 + TOKENS;
    int*   keep1 = top2 + TOKENS;
    int*   keep2 = keep1 + TOKENS;
    int*   cnts  = keep2 + TOKENS;            // 128 * 16 ints (line-padded)
    float* bkey  = (float*)(cnts + 128 * 16); // 128 * CAPSLOT floats
    int*   btok  = (int*)(bkey + 128 * CAPSLOT);

    // ---- try single fused cooperative kernel ----
    if (ks == 16 || ks == 8) {
        void* args[] = { (void*)&x, (void*)&W, (void*)&partial,
                         (void*)&p1, (void*)&p2, (void*)&top1, (void*)&top2,
                         (void*)&cnts, (void*)&bkey, (void*)&btok,
                         (void*)&keep1, (void*)&keep2, (void*)&out };
        hipError_t err;
        if (ks == 16) {
            err = hipLaunchCooperativeKernel(
                reinterpret_cast<void*>(&k_fused<128>),
                dim3(64 * 16), dim3(256), args, 0, stream);
        } else {
            err = hipLaunchCooperativeKernel(
                reinterpret_cast<void*>(&k_fused<256>),
                dim3(64 * 8), dim3(256), args, 0, stream);
        }
        if (err == hipSuccess) return;        // fused path enqueued
        (void)hipGetLastError();              // clear sticky error, fall back
    }

    // ---- classic 4-kernel fallback ----
    if (ks == 16) {
        k_partial<128><<<64 * 16, 256, 0, stream>>>(x, W, partial, cnts);
        k_route<16><<<TOKENS / 4, 256, 0, stream>>>(
            partial, p1, p2, top1, top2, cnts, bkey, btok);
    } else if (ks == 8) {
        k_partial<256><<<64 * 8, 256, 0, stream>>>(x, W, partial, cnts);
        k_route<8><<<TOKENS / 4, 256, 0, stream>>>(
            partial, p1, p2, top1, top2, cnts, bkey, btok);
    } else {
        k_partial<512><<<64 * 4, 256, 0, stream>>>(x, W, partial, cnts);
        k_route<4><<<TOKENS / 4, 256, 0, stream>>>(
            partial, p1, p2, top1, top2, cnts, bkey, btok);
    }
    k_rank<<<2 * EXPERTS, 256, 0, stream>>>(cnts, bkey, btok, keep1, keep2);
    k_out<<<TOKENS / 16, 256, 0, stream>>>(
        p1, p2, top1, top2, keep1, keep2, out);
}

// Round 7
// 281.798 us; speedup vs baseline: 4.8405x; 4.8405x over previous
//
#include <hip/hip_runtime.h>
#include <math.h>

// Problem constants (fixed by reference).
#define TOKENS      16384     // 8 * 2048
#define HID         2048
#define EXPERTS     64
#define CAPSLOT     1024      // per-expert list cap; counts ~Binom(16384,1/64)=256±16
#define CAP         512       // expert_capacity = 2*ceil(16384/64)

__device__ __forceinline__ void fma8(float* a, float s, float4 w0, float4 w1) {
    a[0] = fmaf(s, w0.x, a[0]); a[1] = fmaf(s, w0.y, a[1]);
    a[2] = fmaf(s, w0.z, a[2]); a[3] = fmaf(s, w0.w, a[3]);
    a[4] = fmaf(s, w1.x, a[4]); a[5] = fmaf(s, w1.y, a[5]);
    a[6] = fmaf(s, w1.z, a[6]); a[7] = fmaf(s, w1.w, a[7]);
}

// ---------------------------------------------------------------------------
// K1 (primary): partial logits GEMM, 16-token x 8-expert thread tile.
// SESSION EVIDENCE: r0 (1 wave/SIMD) VALUBusy 35%, r5 (2 waves/SIMD) 37% --
// +2% from 2x waves => a shared per-CU pipe is saturated, not latency.
// Per k4-step the old 8tok tile demanded 8KB LDS W-return (8x b128, each an
// 8-way eg-broadcast of the same 1KB of W) + 64 TA lookups per 512
// FMA-cycles; at 8 waves/CU that is exactly LDS peak (128B/cyc).
// acc=128 (16tok x 8exp) halves BOTH demands per FMA-cycle.
//   KCH=128 -> W chunk 32KB LDS; block = 4 waves x 128 tok = 512 tokens;
//   grid = 32 tb x 16 kc = 512 = 2 blocks/CU = 2 waves/SIMD.
//   __launch_bounds__(256,2): VGPR cap 256, demand ~232 (acc128+xv64+w32).
//   #pragma unroll 1 on the k-loop: r3/r6 spills both came from unroll
//   duplicating live ranges against a tight cap -- forbid it.
// No intra-wave prefetch: 2-wave TLP covers per-step load latency.
// Block 0 zeroes bucket counters for k_route (saves the memset dispatch).
// ---------------------------------------------------------------------------
__global__ __launch_bounds__(256, 2) void k_partial16(
    const float* __restrict__ x, const float* __restrict__ W,
    float* __restrict__ partial, int* __restrict__ cnts)
{
    __shared__ float wl[128 * EXPERTS];   // 32 KB

    const int tid = threadIdx.x;
    const int tb = blockIdx.x & 31;       // token block (512 tokens)
    const int kc = blockIdx.x >> 5;       // k chunk 0..15
    const int k0 = kc * 128;

    if (blockIdx.x == 0) {                // zero bucket counters for k_route
        for (int i = tid; i < 128 * 16; i += 256) cnts[i] = 0;
    }

    // stage W chunk (128 x 64 = 32 KB), coalesced float4
    {
        const float4* src = (const float4*)(W + (size_t)k0 * EXPERTS);
        float4* dst = (float4*)wl;
        #pragma unroll
        for (int i = 0; i < 8; ++i)       // 2048 float4 / 256 threads
            dst[i * 256 + tid] = src[i * 256 + tid];
    }
    __syncthreads();

    const int lane = tid & 63;
    const int wv   = tid >> 6;            // wave 0..3
    const int tg   = lane >> 3;           // token group 0..7 (16 tokens each)
    const int eg   = lane & 7;            // expert group 0..7 (8 experts each)
    const int tok0 = tb * 512 + wv * 128 + tg * 16;
    const float* xb = x + (size_t)tok0 * HID + k0;

    float acc[16][8];
    #pragma unroll
    for (int i = 0; i < 16; ++i)
        #pragma unroll
        for (int e = 0; e < 8; ++e) acc[i][e] = 0.f;

    #pragma unroll 1
    for (int k4 = 0; k4 < 128; k4 += 4) {
        float4 xv[16];
        #pragma unroll
        for (int i = 0; i < 16; ++i)
            xv[i] = *(const float4*)(xb + (size_t)i * HID + k4);

        float4 w0[4], w1[4];
        #pragma unroll
        for (int kk = 0; kk < 4; ++kk) {
            const float* wp = &wl[(k4 + kk) * EXPERTS + eg * 8];
            w0[kk] = *(const float4*)wp;
            w1[kk] = *(const float4*)(wp + 4);
        }

        #pragma unroll
        for (int i = 0; i < 16; ++i) {
            fma8(acc[i], xv[i].x, w0[0], w1[0]);
            fma8(acc[i], xv[i].y, w0[1], w1[1]);
            fma8(acc[i], xv[i].z, w0[2], w1[2]);
            fma8(acc[i], xv[i].w, w0[3], w1[3]);
        }
    }

    float* pb = partial + ((size_t)kc * TOKENS + tok0) * EXPERTS + eg * 8;
    #pragma unroll
    for (int i = 0; i < 16; ++i) {
        *(float4*)(pb + (size_t)i * EXPERTS) =
            make_float4(acc[i][0], acc[i][1], acc[i][2], acc[i][3]);
        *(float4*)(pb + (size_t)i * EXPERTS + 4) =
            make_float4(acc[i][4], acc[i][5], acc[i][6], acc[i][7]);
    }
}

// ---------------------------------------------------------------------------
// K1 (fallback, r5-proven): 8tok x 8exp tile, KCH k per chunk.
// ---------------------------------------------------------------------------
template<int KCH>
__global__ __launch_bounds__(256) void k_partial8(
    const float* __restrict__ x, const float* __restrict__ W,
    float* __restrict__ partial, int* __restrict__ cnts)
{
    __shared__ float wl[KCH * EXPERTS];

    const int tid = threadIdx.x;
    const int tb = blockIdx.x & 63;
    const int kc = blockIdx.x >> 6;
    const int k0 = kc * KCH;

    if (blockIdx.x == 0) {
        for (int i = tid; i < 128 * 16; i += 256) cnts[i] = 0;
    }

    {
        const float4* src = (const float4*)(W + (size_t)k0 * EXPERTS);
        float4* dst = (float4*)wl;
        #pragma unroll
        for (int i = 0; i < (KCH * EXPERTS / 4) / 256; ++i)
            dst[i * 256 + tid] = src[i * 256 + tid];
    }
    __syncthreads();

    const int lane = tid & 63;
    const int wv   = tid >> 6;
    const int tg   = lane >> 3;
    const int eg   = lane & 7;
    const int tok0 = tb * 256 + wv * 64 + tg * 8;
    const float* xb = x + (size_t)tok0 * HID + k0;

    float acc[8][8];
    #pragma unroll
    for (int i = 0; i < 8; ++i)
        #pragma unroll
        for (int e = 0; e < 8; ++e) acc[i][e] = 0.f;

    float4 xv[8];
    #pragma unroll
    for (int i = 0; i < 8; ++i)
        xv[i] = *(const float4*)(xb + (size_t)i * HID);

    #pragma unroll 2
    for (int k4 = 0; k4 < KCH; k4 += 4) {
        float4 xn[8];
        const bool more = (k4 + 4 < KCH);
        if (more) {
            #pragma unroll
            for (int i = 0; i < 8; ++i)
                xn[i] = *(const float4*)(xb + (size_t)i * HID + k4 + 4);
        }

        float4 w0[4], w1[4];
        #pragma unroll
        for (int kk = 0; kk < 4; ++kk) {
            const float* wp = &wl[(k4 + kk) * EXPERTS + eg * 8];
            w0[kk] = *(const float4*)wp;
            w1[kk] = *(const float4*)(wp + 4);
        }

        #pragma unroll
        for (int i = 0; i < 8; ++i) {
            fma8(acc[i], xv[i].x, w0[0], w1[0]);
            fma8(acc[i], xv[i].y, w0[1], w1[1]);
            fma8(acc[i], xv[i].z, w0[2], w1[2]);
            fma8(acc[i], xv[i].w, w0[3], w1[3]);
        }

        if (more) {
            #pragma unroll
            for (int i = 0; i < 8; ++i) xv[i] = xn[i];
        }
    }

    float* pb = partial + ((size_t)kc * TOKENS + tok0) * EXPERTS + eg * 8;
    #pragma unroll
    for (int i = 0; i < 8; ++i) {
        *(float4*)(pb + (size_t)i * EXPERTS) =
            make_float4(acc[i][0], acc[i][1], acc[i][2], acc[i][3]);
        *(float4*)(pb + (size_t)i * EXPERTS + 4) =
            make_float4(acc[i][4], acc[i][5], acc[i][6], acc[i][7]);
    }
}

// ---------------------------------------------------------------------------
// K2: reduce k-chunks + softmax + top1/top2 + bucket append (r5-proven).
// Wave = 1 token x 64 expert lanes; lane 0 appends (p1, token) to the
// per-expert bucket lists via global atomics (line-padded counters).
// ---------------------------------------------------------------------------
template<int KSPLIT>
__global__ __launch_bounds__(256) void k_route(
    const float* __restrict__ partial,
    float* __restrict__ p1o, float* __restrict__ p2o,
    int* __restrict__ top1o, int* __restrict__ top2o,
    int* __restrict__ cnts, float* __restrict__ bkey, int* __restrict__ btok)
{
    const int tid   = threadIdx.x;
    const int e     = tid & 63;
    const int token = blockIdx.x * 4 + (tid >> 6);

    float logit = 0.f;
    #pragma unroll
    for (int c = 0; c < KSPLIT; ++c)
        logit += partial[((size_t)c * TOKENS + token) * EXPERTS + e];

    // top-1 argmax, first-index tie-break
    float bv = logit; int be = e;
    #pragma unroll
    for (int m = 32; m >= 1; m >>= 1) {
        float ov = __shfl_xor(bv, m);
        int   oe = __shfl_xor(be, m);
        if (ov > bv || (ov == bv && oe < be)) { bv = ov; be = oe; }
    }
    const float m1 = bv;
    const int   e1 = be;

    // top-2: argmax excluding e1
    float bv2 = (e == e1) ? -INFINITY : logit;
    int   be2 = (e == e1) ? (1 << 30) : e;
    #pragma unroll
    for (int m = 32; m >= 1; m >>= 1) {
        float ov = __shfl_xor(bv2, m);
        int   oe = __shfl_xor(be2, m);
        if (ov > bv2 || (ov == bv2 && oe < be2)) { bv2 = ov; be2 = oe; }
    }
    const int e2 = be2;

    // softmax denominator (max-subtracted)
    float s = expf(logit - m1);
    #pragma unroll
    for (int m = 32; m >= 1; m >>= 1) s += __shfl_xor(s, m);

    if (e == 0) {
        const float P1 = 1.0f / s;          // max softmax prob (sort key)
        p1o[token]   = P1;
        p2o[token]   = expf(bv2 - m1) / s;
        top1o[token] = e1;
        top2o[token] = e2;

        // bucket appends (fill order nondeterministic; rank comparator
        // (key desc, token asc) is a strict total order -> deterministic)
        int s1 = atomicAdd(&cnts[e1 * 16], 1);
        if (s1 < CAPSLOT) {
            bkey[(size_t)e1 * CAPSLOT + s1] = P1;
            btok[(size_t)e1 * CAPSLOT + s1] = token;
        }
        int s2 = atomicAdd(&cnts[(64 + e2) * 16], 1);
        if (s2 < CAPSLOT) {
            bkey[(size_t)(64 + e2) * CAPSLOT + s2] = P1;
            btok[(size_t)(64 + e2) * CAPSLOT + s2] = token;
        }
    }
}

// ---------------------------------------------------------------------------
// K3: per-expert batch-prioritized ranking -> keep flags (r5-proven).
// 128 blocks; reads its pre-built bucket (~256 entries), O(n^2) rank.
// keep1: rank1 < CAP.  keep2: rank2 + n1_raw < CAP.
// ---------------------------------------------------------------------------
__global__ __launch_bounds__(256) void k_rank(
    const int* __restrict__ cnts,
    const float* __restrict__ bkey, const int* __restrict__ btok,
    int* __restrict__ keep1, int* __restrict__ keep2)
{
    __shared__ float skey[CAPSLOT];
    __shared__ int   stok[CAPSLOT];

    const int b    = blockIdx.x;
    const int mode = b >> 6;
    const int e    = b & 63;
    const int tid  = threadIdx.x;

    const int n_raw = cnts[b * 16];
    const int n     = min(n_raw, CAPSLOT);
    const int base  = mode ? cnts[e * 16] : 0;

    for (int i = tid; i < n; i += 256) {
        skey[i] = bkey[(size_t)b * CAPSLOT + i];
        stok[i] = btok[(size_t)b * CAPSLOT + i];
    }
    __syncthreads();

    int* __restrict__ keep = mode ? keep2 : keep1;
    for (int i = tid; i < n; i += 256) {
        const float ki = skey[i];
        const int   ti = stok[i];
        int r = base;
        for (int j = 0; j < n; ++j)
            r += (skey[j] > ki || (skey[j] == ki && stok[j] < ti)) ? 1 : 0;
        keep[ti] = (r < CAP) ? 1 : 0;
    }
}

// ---------------------------------------------------------------------------
// K4: materialize [top_1_mask | gates], coalesced (16 threads per token row).
// ---------------------------------------------------------------------------
__global__ __launch_bounds__(256) void k_out(
    const float* __restrict__ p1, const float* __restrict__ p2,
    const int* __restrict__ top1, const int* __restrict__ top2,
    const int* __restrict__ keep1, const int* __restrict__ keep2,
    float* __restrict__ out)
{
    const int tid   = threadIdx.x;
    const int token = blockIdx.x * 16 + (tid >> 4);
    const int eb    = (tid & 15) * 4;

    const int  k1 = keep1[token];
    const int  k2 = keep2[token];
    const float P1 = k1 ? p1[token] : 0.0f;
    const float P2 = k2 ? p2[token] : 0.0f;
    const float denom = fmaxf(P1 + P2, 1.1920929e-07f);   // fp32 eps clip
    const float g1 = P1 / denom;
    const float g2 = P2 / denom;
    const int e1 = top1[token];
    const int e2 = top2[token];

    float4 mv, pv;
    mv.x = (k1 && e1 == eb + 0) ? 1.0f : 0.0f;
    mv.y = (k1 && e1 == eb + 1) ? 1.0f : 0.0f;
    mv.z = (k1 && e1 == eb + 2) ? 1.0f : 0.0f;
    mv.w = (k1 && e1 == eb + 3) ? 1.0f : 0.0f;
    pv.x = (k1 && e1 == eb + 0) ? g1 : ((k2 && e2 == eb + 0) ? g2 : 0.0f);
    pv.y = (k1 && e1 == eb + 1) ? g1 : ((k2 && e2 == eb + 1) ? g2 : 0.0f);
    pv.z = (k1 && e1 == eb + 2) ? g1 : ((k2 && e2 == eb + 2) ? g2 : 0.0f);
    pv.w = (k1 && e1 == eb + 3) ? g1 : ((k2 && e2 == eb + 3) ? g2 : 0.0f);

    *(float4*)(out + (size_t)token * EXPERTS + eb) = mv;
    *(float4*)(out + (size_t)TOKENS * EXPERTS + (size_t)token * EXPERTS + eb) = pv;
}

// ---------------------------------------------------------------------------
extern "C" void kernel_launch(void* const* d_in, const int* in_sizes, int n_in,
                              void* d_out, int out_size, void* d_ws, size_t ws_size,
                              hipStream_t stream)
{
    const float* x = (const float*)d_in[0];   // (8,2048,2048) fp32
    const float* W = (const float*)d_in[1];   // (2048,64) fp32
    float* out = (float*)d_out;               // 2 * 16384 * 64 fp32

    // extras: p1,p2 + top1,top2,keep1,keep2 + cnts + buckets  (~1.45 MB)
    const size_t extras_f = 6 * (size_t)TOKENS + 128 * 16
                          + 2 * 128 * (size_t)CAPSLOT;
    const size_t need16 = ((size_t)16 * TOKENS * EXPERTS + extras_f) * 4;
    const size_t need8  = ((size_t)8  * TOKENS * EXPERTS + extras_f) * 4;

    int ks;
    if (ws_size == 0 || ws_size >= need16) ks = 16;
    else if (ws_size >= need8)             ks = 8;
    else                                   ks = 4;

    float* partial = (float*)d_ws;            // ks * TOKENS * EXPERTS floats
    float* p1    = partial + (size_t)ks * TOKENS * EXPERTS;
    float* p2    = p1 + TOKENS;
    int*   top1  = (int*)(p2 + TOKENS);
    int*   top2  = top1 + TOKENS;
    int*   keep1 = top2 + TOKENS;
    int*   keep2 = keep1 + TOKENS;
    int*   cnts  = keep2 + TOKENS;            // 128 * 16 ints (line-padded)
    float* bkey  = (float*)(cnts + 128 * 16); // 128 * CAPSLOT floats
    int*   btok  = (int*)(bkey + 128 * CAPSLOT);

    if (ks == 16) {
        k_partial16<<<32 * 16, 256, 0, stream>>>(x, W, partial, cnts);
        k_route<16><<<TOKENS / 4, 256, 0, stream>>>(
            partial, p1, p2, top1, top2, cnts, bkey, btok);
    } else if (ks == 8) {
        k_partial8<256><<<64 * 8, 256, 0, stream>>>(x, W, partial, cnts);
        k_route<8><<<TOKENS / 4, 256, 0, stream>>>(
            partial, p1, p2, top1, top2, cnts, bkey, btok);
    } else {
        k_partial8<512><<<64 * 4, 256, 0, stream>>>(x, W, partial, cnts);
        k_route<4><<<TOKENS / 4, 256, 0, stream>>>(
            partial, p1, p2, top1, top2, cnts, bkey, btok);
    }
    k_rank<<<2 * EXPERTS, 256, 0, stream>>>(cnts, bkey, btok, keep1, keep2);
    k_out<<<TOKENS / 16, 256, 0, stream>>>(
        p1, p2, top1, top2, keep1, keep2, out);
}